// Round 1
// baseline (2899.234 us; speedup 1.0000x reference)
//
#include <hip/hip_runtime.h>

// LaplaceMeshLoss: COO Laplacian SpMV + per-row norm + weighted scalar reduce.
//
// ws layout:
//   [0,8)            double partial sum
//   [8,24)           int nvpm[4]
//   [32, 32+4V)      float rowsum[V]
//   [32+4V, 32+16V)  float Lx[V*3]
// All zeroed via hipMemsetAsync at launch start (harness poisons ws with 0xAA).

__global__ void scatter_kernel(const float* __restrict__ verts,
                               const float* __restrict__ vals,
                               const int* __restrict__ rows,
                               const int* __restrict__ cols,
                               float* __restrict__ Lx,
                               float* __restrict__ rowsum,
                               int nnz) {
    int i = blockIdx.x * blockDim.x + threadIdx.x;
    if (i >= nnz) return;
    int r = rows[i];
    int c = cols[i];
    float v = vals[i];
    float x = verts[3 * c + 0];
    float y = verts[3 * c + 1];
    float z = verts[3 * c + 2];
    atomicAdd(&Lx[3 * r + 0], v * x);
    atomicAdd(&Lx[3 * r + 1], v * y);
    atomicAdd(&Lx[3 * r + 2], v * z);
    atomicAdd(&rowsum[r], v);
}

// verts_mesh_idx is sorted; nvpm[m] = lower_bound(m+1) - lower_bound(m).
__global__ void mesh_counts_kernel(const int* __restrict__ mesh_idx, int v,
                                   int* __restrict__ nvpm) {
    int m = threadIdx.x;
    if (m >= 4) return;
    auto lb = [&](int t) {
        int lo = 0, hi = v;
        while (lo < hi) {
            int mid = (lo + hi) >> 1;
            if (mesh_idx[mid] < t) lo = mid + 1; else hi = mid;
        }
        return lo;
    };
    nvpm[m] = lb(m + 1) - lb(m);
}

__global__ void finalize_kernel(const float* __restrict__ verts,
                                const float* __restrict__ coefs,
                                const int* __restrict__ mesh_idx,
                                const float* __restrict__ Lx,
                                const float* __restrict__ rowsum,
                                const int* __restrict__ nvpm,
                                double* __restrict__ partial,
                                int v) {
    // Per-mesh inverse counts (4 values, broadcast-loaded).
    float inv0 = 1.0f / (float)nvpm[0];
    float inv1 = 1.0f / (float)nvpm[1];
    float inv2 = 1.0f / (float)nvpm[2];
    float inv3 = 1.0f / (float)nvpm[3];

    double acc = 0.0;
    for (int i = blockIdx.x * blockDim.x + threadIdx.x; i < v;
         i += gridDim.x * blockDim.x) {
        float rs = rowsum[i];
        float nw = (rs > 0.0f) ? (1.0f / rs) : rs;
        float r0 = Lx[3 * i + 0] * nw - verts[3 * i + 0];
        float r1 = Lx[3 * i + 1] * nw - verts[3 * i + 1];
        float r2 = Lx[3 * i + 2] * nw - verts[3 * i + 2];
        float loss = sqrtf(r0 * r0 + r1 * r1 + r2 * r2);
        int m = mesh_idx[i];
        float w = (m == 0) ? inv0 : (m == 1) ? inv1 : (m == 2) ? inv2 : inv3;
        acc += (double)(loss * w * coefs[i]);
    }

    // Block reduction in double via LDS.
    __shared__ double sred[256];
    sred[threadIdx.x] = acc;
    __syncthreads();
    for (int s = blockDim.x / 2; s > 0; s >>= 1) {
        if (threadIdx.x < s) sred[threadIdx.x] += sred[threadIdx.x + s];
        __syncthreads();
    }
    if (threadIdx.x == 0) atomicAdd(partial, sred[0]);
}

__global__ void write_out_kernel(const double* __restrict__ partial,
                                 float* __restrict__ out) {
    if (threadIdx.x == 0 && blockIdx.x == 0) {
        out[0] = (float)(partial[0] * 0.25);  // / N_MESHES
    }
}

extern "C" void kernel_launch(void* const* d_in, const int* in_sizes, int n_in,
                              void* d_out, int out_size, void* d_ws, size_t ws_size,
                              hipStream_t stream) {
    const float* verts    = (const float*)d_in[0];
    const float* lap_vals = (const float*)d_in[1];
    const int*   lap_rows = (const int*)d_in[2];
    const int*   lap_cols = (const int*)d_in[3];
    const int*   mesh_idx = (const int*)d_in[4];
    const float* coefs    = (const float*)d_in[5];
    float* out = (float*)d_out;

    const int V   = in_sizes[0] / 3;
    const int NNZ = in_sizes[1];

    char* ws = (char*)d_ws;
    double* partial = (double*)(ws + 0);
    int*    nvpm    = (int*)(ws + 8);
    float*  rowsum  = (float*)(ws + 32);
    float*  Lx      = (float*)(ws + 32 + (size_t)4 * V);

    size_t zero_bytes = 32 + (size_t)16 * V;
    hipMemsetAsync(d_ws, 0, zero_bytes, stream);

    mesh_counts_kernel<<<1, 64, 0, stream>>>(mesh_idx, V, nvpm);

    {
        int threads = 256;
        int blocks = (NNZ + threads - 1) / threads;
        scatter_kernel<<<blocks, threads, 0, stream>>>(
            verts, lap_vals, lap_rows, lap_cols, Lx, rowsum, NNZ);
    }

    {
        int threads = 256;
        int blocks = 2048;  // grid-stride over V=2M
        finalize_kernel<<<blocks, threads, 0, stream>>>(
            verts, coefs, mesh_idx, Lx, rowsum, nvpm, partial, V);
    }

    write_out_kernel<<<1, 64, 0, stream>>>(partial, out);
}